// Round 4
// baseline (486.973 us; speedup 1.0000x reference)
//
#include <hip/hip_runtime.h>
#include <stdint.h>

typedef uint16_t u16;
typedef uint32_t u32;
typedef __bf16 bf16_t;
typedef bf16_t bf16x8 __attribute__((ext_vector_type(8)));
typedef float f32x4 __attribute__((ext_vector_type(4)));
typedef u16 u16x4 __attribute__((ext_vector_type(4)));
typedef u16 u16x8 __attribute__((ext_vector_type(8)));

__device__ __forceinline__ float bf2f(u16 v) {
    union { u32 u; float f; } x; x.u = ((u32)v) << 16; return x.f;
}
__device__ __forceinline__ u16 f2bf(float f) {
    union { float f; u32 u; } x; x.f = f;
    u32 r = (x.u + 0x7fffu + ((x.u >> 16) & 1u)) >> 16;
    return (u16)r;
}

// async 16B/lane global->LDS. HW writes lane i at (wave-uniform lds base)+i*16.
__device__ __forceinline__ void gload_lds16(const u16* g, u16* l) {
    __builtin_amdgcn_global_load_lds(
        (const __attribute__((address_space(1))) void*)g,
        (__attribute__((address_space(3))) void*)l,
        16, 0, 0);
}
#define WAIT_ALL() __builtin_amdgcn_s_waitcnt(0)

// ---------------------------------------------------------------------------
// Convert fp32 -> bf16, vectorized x4.
// ---------------------------------------------------------------------------
__global__ __launch_bounds__(256) void cvt_kernel(
    const float* __restrict__ src, u16* __restrict__ dst, int n4)
{
    int i = blockIdx.x * 256 + threadIdx.x;
    if (i >= n4) return;
    f32x4 v = ((const f32x4*)src)[i];
    u16x4 o;
#pragma unroll
    for (int j = 0; j < 4; j++) o[j] = f2bf(v[j]);
    ((u16x4*)dst)[i] = o;
}

// ---------------------------------------------------------------------------
// LayerNorm over D=1024, one block (256 thr) per token row. fp32 in, bf16 out.
// ---------------------------------------------------------------------------
__global__ __launch_bounds__(256) void ln_kernel(
    const float* __restrict__ x, const float* __restrict__ g,
    const float* __restrict__ b, u16* __restrict__ out)
{
    const int row = blockIdx.x;
    const int tid = threadIdx.x;
    f32x4 xv = *(const f32x4*)(x + (size_t)row * 1024 + tid * 4);
    float v[4];
    float s = 0.f, s2 = 0.f;
#pragma unroll
    for (int i = 0; i < 4; i++) { v[i] = xv[i]; s += v[i]; s2 += v[i] * v[i]; }
#pragma unroll
    for (int off = 1; off < 64; off <<= 1) {
        s  += __shfl_xor(s, off);
        s2 += __shfl_xor(s2, off);
    }
    __shared__ float ws1[4], ws2[4];
    if ((tid & 63) == 0) { ws1[tid >> 6] = s; ws2[tid >> 6] = s2; }
    __syncthreads();
    s  = ws1[0] + ws1[1] + ws1[2] + ws1[3];
    s2 = ws2[0] + ws2[1] + ws2[2] + ws2[3];
    float mu  = s * (1.0f / 1024.0f);
    float var = s2 * (1.0f / 1024.0f) - mu * mu;
    float rstd = rsqrtf(var + 1e-5f);
    f32x4 gv = *(const f32x4*)(g + tid * 4);
    f32x4 bv = *(const f32x4*)(b + tid * 4);
    u16x4 ov;
#pragma unroll
    for (int i = 0; i < 4; i++)
        ov[i] = f2bf((v[i] - mu) * rstd * gv[i] + bv[i]);
    *(u16x4*)(out + (size_t)row * 1024 + tid * 4) = ov;
}

// ---------------------------------------------------------------------------
// GEMM: C[M,N] = A[M,K] @ Bt[N,K]^T + bias (+ gelu) (+ fp32 residual).
// A/Bt bf16, A row stride lda, bias fp32. If res != null: C is fp32 and
// C[idx] = acc + bias + res[idx] (res/C may alias in-place; same thread reads
// res[idx] before writing C[idx]). Else: C is bf16.
// 128x128 tile, BK=32, 4 waves (2x2), 4x4 16x16x32 MFMAs/wave (m97 structure).
// ---------------------------------------------------------------------------
__global__ __launch_bounds__(256, 2) void gemm_bt(
    const u16* __restrict__ A, const u16* __restrict__ Bt,
    const float* __restrict__ bias, const float* res,
    void* C, int N, int K, int lda, int gelu)
{
    __shared__ __align__(16) u16 sA[128 * 32];
    __shared__ __align__(16) u16 sB[128 * 32];
    const int tid  = threadIdx.x;
    const int wave = tid >> 6, lane = tid & 63;
    const int lm = lane & 15, quad = lane >> 4;
    const int wm = wave >> 1, wn = wave & 1;
    const int row0 = blockIdx.y * 128, col0 = blockIdx.x * 128;
    const int r16 = lane >> 2;
    const int c8  = (lane & 3) * 8;

    f32x4 acc[4][4];
#pragma unroll
    for (int i = 0; i < 4; i++)
#pragma unroll
        for (int j = 0; j < 4; j++) acc[i][j] = f32x4{0.f, 0.f, 0.f, 0.f};

    for (int k0 = 0; k0 < K; k0 += 32) {
        __syncthreads();
        if (wave < 2) {
#pragma unroll
            for (int j = 0; j < 4; j++) {
                int chunk = wave * 4 + j;
                int r = chunk * 16 + r16;
                gload_lds16(A + (size_t)(row0 + r) * lda + k0 + c8, &sA[chunk * 512]);
            }
        } else {
#pragma unroll
            for (int j = 0; j < 4; j++) {
                int chunk = (wave - 2) * 4 + j;
                int r = chunk * 16 + r16;
                gload_lds16(Bt + (size_t)(col0 + r) * K + k0 + c8, &sB[chunk * 512]);
            }
        }
        WAIT_ALL();
        __syncthreads();

        bf16x8 af[4], bfr[4];
#pragma unroll
        for (int t = 0; t < 4; t++)
            af[t] = *(const bf16x8*)&sA[(wm * 64 + t * 16 + lm) * 32 + quad * 8];
#pragma unroll
        for (int t = 0; t < 4; t++)
            bfr[t] = *(const bf16x8*)&sB[(wn * 64 + t * 16 + lm) * 32 + quad * 8];
#pragma unroll
        for (int i = 0; i < 4; i++)
#pragma unroll
            for (int j = 0; j < 4; j++)
                acc[i][j] = __builtin_amdgcn_mfma_f32_16x16x32_bf16(af[i], bfr[j], acc[i][j], 0, 0, 0);
    }

    // epilogue. C/D layout: col = lane&15, row = quad*4 + reg  (m89-verified)
    float bj[4];
#pragma unroll
    for (int j = 0; j < 4; j++) bj[j] = bias[col0 + wn * 64 + j * 16 + lm];
#pragma unroll
    for (int i = 0; i < 4; i++) {
        int rbase = row0 + wm * 64 + i * 16 + quad * 4;
#pragma unroll
        for (int j = 0; j < 4; j++) {
            int c = col0 + wn * 64 + j * 16 + lm;
#pragma unroll
            for (int r = 0; r < 4; r++) {
                float v = acc[i][j][r] + bj[j];
                if (gelu) v = 0.5f * v * (1.0f + erff(v * 0.70710678118f));
                size_t idx = (size_t)(rbase + r) * N + c;
                if (res) {
                    ((float*)C)[idx] = v + res[idx];
                } else {
                    ((u16*)C)[idx] = f2bf(v);
                }
            }
        }
    }
}

// ---------------------------------------------------------------------------
// Causal flash attention, IN-PLACE on qkv [4096][3072] bf16 (q|k|v, head h at
// col h*64); output overwrites the Q columns (each block reads its own Q tile
// into LDS before any O write; writes touch only own rows x own head's Q cols;
// K/V cols never written -> race-free). Block = 4 waves = 128 q rows of (b,h).
// ---------------------------------------------------------------------------
__global__ __launch_bounds__(256, 2) void attn_kernel(u16* qkv)
{
    __shared__ __align__(16) u16 sQ[128 * 64];
    __shared__ __align__(16) u16 sK[64 * 64];
    __shared__ __align__(16) u16 sVT[64 * 72];
    __shared__ __align__(16) u16 sP[4 * 32 * 64];

    const int tid  = threadIdx.x;
    const int wave = tid >> 6, lane = tid & 63;
    const int lm = lane & 15, quad = lane >> 4;
    const int q0 = blockIdx.x * 128;
    const int b = blockIdx.y >> 4, h = blockIdx.y & 15;
    const size_t tok0 = (size_t)b * 2048;
    const int qcol = h * 64, kcol = 1024 + h * 64, vcol = 2048 + h * 64;
    const int r8 = lane >> 3;
    const int c8 = (lane & 7) * 8;

#pragma unroll
    for (int j = 0; j < 4; j++) {
        int chunk = wave * 4 + j;
        int r = chunk * 8 + r8;
        gload_lds16(qkv + (tok0 + q0 + r) * 3072 + qcol + c8, &sQ[chunk * 512]);
    }
    WAIT_ALL();
    __syncthreads();

    bf16x8 aq[2][2];
#pragma unroll
    for (int m = 0; m < 2; m++)
#pragma unroll
        for (int kk = 0; kk < 2; kk++)
            aq[m][kk] = *(const bf16x8*)&sQ[(wave * 32 + m * 16 + lm) * 64 + kk * 32 + quad * 8];

    f32x4 oacc[2][4];
    float mrun[2][4], lrun[2][4];
#pragma unroll
    for (int m = 0; m < 2; m++) {
#pragma unroll
        for (int n = 0; n < 4; n++) oacc[m][n] = f32x4{0.f, 0.f, 0.f, 0.f};
#pragma unroll
        for (int r = 0; r < 4; r++) { mrun[m][r] = -1e30f; lrun[m][r] = 0.f; }
    }

    const int ntiles = q0 / 64 + 2;
    for (int tk = 0; tk < ntiles; tk++) {
        const int kb = tk * 64;
        __syncthreads();
#pragma unroll
        for (int j = 0; j < 2; j++) {
            int chunk = wave * 2 + j;
            int r = chunk * 8 + r8;
            gload_lds16(qkv + (tok0 + kb + r) * 3072 + kcol + c8, &sK[chunk * 512]);
        }
        {
            int kkey = tid >> 2;
            int dq = (tid & 3) * 16;
            const u16* vr = qkv + (tok0 + kb + kkey) * 3072 + vcol + dq;
            u16x8 v0 = *(const u16x8*)vr;
            u16x8 v1 = *(const u16x8*)(vr + 8);
#pragma unroll
            for (int i = 0; i < 8; i++) sVT[(dq + i) * 72 + kkey] = v0[i];
#pragma unroll
            for (int i = 0; i < 8; i++) sVT[(dq + 8 + i) * 72 + kkey] = v1[i];
        }
        WAIT_ALL();
        __syncthreads();

        bool active = (kb <= q0 + wave * 32 + 31);
        if (active) {
            float sc[2][4][4];
#pragma unroll
            for (int m = 0; m < 2; m++) {
#pragma unroll
                for (int n = 0; n < 4; n++) {
                    f32x4 s = f32x4{0.f, 0.f, 0.f, 0.f};
#pragma unroll
                    for (int kk = 0; kk < 2; kk++) {
                        bf16x8 bk = *(const bf16x8*)&sK[(n * 16 + lm) * 64 + kk * 32 + quad * 8];
                        s = __builtin_amdgcn_mfma_f32_16x16x32_bf16(aq[m][kk], bk, s, 0, 0, 0);
                    }
                    int col  = kb + n * 16 + lm;
                    int rowb = q0 + wave * 32 + m * 16 + quad * 4;
#pragma unroll
                    for (int r = 0; r < 4; r++)
                        sc[m][n][r] = (col <= rowb + r) ? s[r] * 0.125f : -1e30f;
                }
            }
#pragma unroll
            for (int m = 0; m < 2; m++) {
#pragma unroll
                for (int r = 0; r < 4; r++) {
                    float mx = fmaxf(fmaxf(sc[m][0][r], sc[m][1][r]),
                                     fmaxf(sc[m][2][r], sc[m][3][r]));
#pragma unroll
                    for (int off = 1; off < 16; off <<= 1) mx = fmaxf(mx, __shfl_xor(mx, off));
                    float mnew  = fmaxf(mrun[m][r], mx);
                    float alpha = __expf(mrun[m][r] - mnew);
                    float sum = 0.f;
#pragma unroll
                    for (int n = 0; n < 4; n++) {
                        float p = __expf(sc[m][n][r] - mnew);
                        sc[m][n][r] = p;
                        sum += p;
                    }
#pragma unroll
                    for (int off = 1; off < 16; off <<= 1) sum += __shfl_xor(sum, off);
                    lrun[m][r] = lrun[m][r] * alpha + sum;
                    mrun[m][r] = mnew;
#pragma unroll
                    for (int n = 0; n < 4; n++) oacc[m][n][r] *= alpha;
                }
            }
#pragma unroll
            for (int m = 0; m < 2; m++)
#pragma unroll
                for (int n = 0; n < 4; n++)
#pragma unroll
                    for (int r = 0; r < 4; r++)
                        sP[wave * 2048 + (m * 16 + quad * 4 + r) * 64 + n * 16 + lm] =
                            f2bf(sc[m][n][r]);
#pragma unroll
            for (int m = 0; m < 2; m++) {
                bf16x8 ap[2];
#pragma unroll
                for (int kk = 0; kk < 2; kk++)
                    ap[kk] = *(const bf16x8*)&sP[wave * 2048 + (m * 16 + lm) * 64 + kk * 32 + quad * 8];
#pragma unroll
                for (int n = 0; n < 4; n++)
#pragma unroll
                    for (int kk = 0; kk < 2; kk++) {
                        bf16x8 bv = *(const bf16x8*)&sVT[(n * 16 + lm) * 72 + kk * 32 + quad * 8];
                        oacc[m][n] = __builtin_amdgcn_mfma_f32_16x16x32_bf16(ap[kk], bv, oacc[m][n], 0, 0, 0);
                    }
            }
        }
    }

#pragma unroll
    for (int m = 0; m < 2; m++) {
        int rowb = q0 + wave * 32 + m * 16 + quad * 4;
#pragma unroll
        for (int r = 0; r < 4; r++) {
            float inv = 1.0f / lrun[m][r];
#pragma unroll
            for (int n = 0; n < 4; n++) {
                int d = n * 16 + lm;
                qkv[(tok0 + rowb + r) * 3072 + qcol + d] = f2bf(oacc[m][n][r] * inv);
            }
        }
    }
}

// ---------------------------------------------------------------------------
extern "C" void kernel_launch(void* const* d_in, const int* in_sizes, int n_in,
                              void* d_out, int out_size, void* d_ws, size_t ws_size,
                              hipStream_t stream)
{
    (void)in_sizes; (void)n_in; (void)out_size; (void)ws_size;
    const float* x    = (const float*)d_in[0];
    const float* ln1g = (const float*)d_in[1];
    const float* ln1b = (const float*)d_in[2];
    const float* qkvwF= (const float*)d_in[3];
    const float* qkvb = (const float*)d_in[4];
    const float* outwF= (const float*)d_in[5];
    const float* outb = (const float*)d_in[6];
    const float* ln2g = (const float*)d_in[7];
    const float* ln2b = (const float*)d_in[8];
    const float* fc1wF= (const float*)d_in[9];
    const float* fc1b = (const float*)d_in[10];
    const float* fc2wF= (const float*)d_in[11];
    const float* fc2b = (const float*)d_in[12];
    float* out = (float*)d_out;          // fp32 output / residual stream x1
    u16*   ws  = (u16*)d_ws;
    const int M1 = 1 << 20;

    // ws layout (u16 elems), total 28M = 56 MB:
    //   qkvw' [0,3M)  outw' [3M,4M)  qkvB [4M,16M)  fc1w' [16M,20M)
    //   fc2w' [20M,24M)  h [24M,28M)
    //   ff1 overlays [0,16M)  (qkvw'/outw'/qkvB all dead after step 4)
    u16* qkvw = ws;
    u16* outw = ws + 3 * M1;
    u16* qkvB = ws + 4 * M1;
    u16* ff1  = ws;
    u16* fc1w = ws + 16 * M1;
    u16* fc2w = ws + 20 * M1;
    u16* h    = ws + 24 * M1;

    // 0. convert the 4 big weights fp32 -> bf16
    cvt_kernel<<<3072, 256, 0, stream>>>(qkvwF, qkvw, 3 * M1 / 4);
    cvt_kernel<<<1024, 256, 0, stream>>>(outwF, outw, 1 * M1 / 4);
    cvt_kernel<<<4096, 256, 0, stream>>>(fc1wF, fc1w, 4 * M1 / 4);
    cvt_kernel<<<4096, 256, 0, stream>>>(fc2wF, fc2w, 4 * M1 / 4);

    // 1. h = LN1(x)
    ln_kernel<<<4096, 256, 0, stream>>>(x, ln1g, ln1b, h);
    // 2. qkvB = h @ qkv_w^T + qkv_b   (bf16 out)
    gemm_bt<<<dim3(24, 32), 256, 0, stream>>>(h, qkvw, qkvb, nullptr, qkvB,
                                              3072, 1024, 1024, 0);
    // 3. causal flash attention, O written into Q cols of qkvB
    attn_kernel<<<dim3(16, 32), 256, 0, stream>>>(qkvB);
    // 4. x1(=d_out, fp32) = x + O @ out_w^T + out_b   (A = qkvB Q-cols, lda=3072)
    gemm_bt<<<dim3(8, 32), 256, 0, stream>>>(qkvB, outw, outb, x, out,
                                             1024, 1024, 3072, 0);
    // 5. h = LN2(x1)
    ln_kernel<<<4096, 256, 0, stream>>>(out, ln2g, ln2b, h);
    // 6. ff1 = gelu(h @ fc1_w^T + fc1_b)   (bf16, overlays dead qkv region)
    gemm_bt<<<dim3(32, 32), 256, 0, stream>>>(h, fc1w, fc1b, nullptr, ff1,
                                              4096, 1024, 1024, 1);
    // 7. out = x1 + ff1 @ fc2_w^T + fc2_b   (fp32, in-place residual)
    gemm_bt<<<dim3(8, 32), 256, 0, stream>>>(ff1, fc2w, fc2b, out, out,
                                             1024, 4096, 4096, 0);
}

// Round 5
// 439.336 us; speedup vs baseline: 1.1084x; 1.1084x over previous
//
#include <hip/hip_runtime.h>
#include <stdint.h>

typedef uint16_t u16;
typedef uint32_t u32;
typedef __bf16 bf16_t;
typedef bf16_t bf16x8 __attribute__((ext_vector_type(8)));
typedef float f32x4 __attribute__((ext_vector_type(4)));
typedef u16 u16x4 __attribute__((ext_vector_type(4)));
typedef u16 u16x8 __attribute__((ext_vector_type(8)));

__device__ __forceinline__ float bf2f(u16 v) {
    union { u32 u; float f; } x; x.u = ((u32)v) << 16; return x.f;
}
__device__ __forceinline__ u16 f2bf(float f) {
    union { float f; u32 u; } x; x.f = f;
    u32 r = (x.u + 0x7fffu + ((x.u >> 16) & 1u)) >> 16;
    return (u16)r;
}

// async 16B/lane global->LDS. HW writes lane i at (wave-uniform lds base)+i*16.
__device__ __forceinline__ void gload_lds16(const u16* g, u16* l) {
    __builtin_amdgcn_global_load_lds(
        (const __attribute__((address_space(1))) void*)g,
        (__attribute__((address_space(3))) void*)l,
        16, 0, 0);
}
#define WAIT_ALL() __builtin_amdgcn_s_waitcnt(0)

// ---------------------------------------------------------------------------
// Convert fp32 -> bf16, vectorized x4.
// ---------------------------------------------------------------------------
__global__ __launch_bounds__(256) void cvt_kernel(
    const float* __restrict__ src, u16* __restrict__ dst, int n4)
{
    int i = blockIdx.x * 256 + threadIdx.x;
    if (i >= n4) return;
    f32x4 v = ((const f32x4*)src)[i];
    u16x4 o;
#pragma unroll
    for (int j = 0; j < 4; j++) o[j] = f2bf(v[j]);
    ((u16x4*)dst)[i] = o;
}

// ---------------------------------------------------------------------------
// LayerNorm over D=1024, one block (256 thr) per token row. fp32 in, bf16 out.
// ---------------------------------------------------------------------------
__global__ __launch_bounds__(256) void ln_kernel(
    const float* __restrict__ x, const float* __restrict__ g,
    const float* __restrict__ b, u16* __restrict__ out)
{
    const int row = blockIdx.x;
    const int tid = threadIdx.x;
    f32x4 xv = *(const f32x4*)(x + (size_t)row * 1024 + tid * 4);
    float v[4];
    float s = 0.f, s2 = 0.f;
#pragma unroll
    for (int i = 0; i < 4; i++) { v[i] = xv[i]; s += v[i]; s2 += v[i] * v[i]; }
#pragma unroll
    for (int off = 1; off < 64; off <<= 1) {
        s  += __shfl_xor(s, off);
        s2 += __shfl_xor(s2, off);
    }
    __shared__ float ws1[4], ws2[4];
    if ((tid & 63) == 0) { ws1[tid >> 6] = s; ws2[tid >> 6] = s2; }
    __syncthreads();
    s  = ws1[0] + ws1[1] + ws1[2] + ws1[3];
    s2 = ws2[0] + ws2[1] + ws2[2] + ws2[3];
    float mu  = s * (1.0f / 1024.0f);
    float var = s2 * (1.0f / 1024.0f) - mu * mu;
    float rstd = rsqrtf(var + 1e-5f);
    f32x4 gv = *(const f32x4*)(g + tid * 4);
    f32x4 bv = *(const f32x4*)(b + tid * 4);
    u16x4 ov;
#pragma unroll
    for (int i = 0; i < 4; i++)
        ov[i] = f2bf((v[i] - mu) * rstd * gv[i] + bv[i]);
    *(u16x4*)(out + (size_t)row * 1024 + tid * 4) = ov;
}

// ---------------------------------------------------------------------------
// GEMM 128x128: C[M,N] = A[M,K] @ Bt[N,K]^T + bias (+ gelu) (+ fp32 residual).
// A/Bt bf16, bias fp32. res!=null -> C fp32 (+res, may alias in-place);
// else C bf16. BK=32, 4 waves (2x2), 4x4 16x16x32 MFMAs/wave (m97 structure).
// Use when grid >= 3 blocks/CU (QKV, FC1).
// ---------------------------------------------------------------------------
__global__ __launch_bounds__(256, 2) void gemm_bt(
    const u16* __restrict__ A, const u16* __restrict__ Bt,
    const float* __restrict__ bias, const float* res,
    void* C, int N, int K, int lda, int gelu)
{
    __shared__ __align__(16) u16 sA[128 * 32];
    __shared__ __align__(16) u16 sB[128 * 32];
    const int tid  = threadIdx.x;
    const int wave = tid >> 6, lane = tid & 63;
    const int lm = lane & 15, quad = lane >> 4;
    const int wm = wave >> 1, wn = wave & 1;
    const int row0 = blockIdx.y * 128, col0 = blockIdx.x * 128;
    const int r16 = lane >> 2;
    const int c8  = (lane & 3) * 8;

    f32x4 acc[4][4];
#pragma unroll
    for (int i = 0; i < 4; i++)
#pragma unroll
        for (int j = 0; j < 4; j++) acc[i][j] = f32x4{0.f, 0.f, 0.f, 0.f};

    for (int k0 = 0; k0 < K; k0 += 32) {
        __syncthreads();
        if (wave < 2) {
#pragma unroll
            for (int j = 0; j < 4; j++) {
                int chunk = wave * 4 + j;
                int r = chunk * 16 + r16;
                gload_lds16(A + (size_t)(row0 + r) * lda + k0 + c8, &sA[chunk * 512]);
            }
        } else {
#pragma unroll
            for (int j = 0; j < 4; j++) {
                int chunk = (wave - 2) * 4 + j;
                int r = chunk * 16 + r16;
                gload_lds16(Bt + (size_t)(col0 + r) * K + k0 + c8, &sB[chunk * 512]);
            }
        }
        WAIT_ALL();
        __syncthreads();

        bf16x8 af[4], bfr[4];
#pragma unroll
        for (int t = 0; t < 4; t++)
            af[t] = *(const bf16x8*)&sA[(wm * 64 + t * 16 + lm) * 32 + quad * 8];
#pragma unroll
        for (int t = 0; t < 4; t++)
            bfr[t] = *(const bf16x8*)&sB[(wn * 64 + t * 16 + lm) * 32 + quad * 8];
#pragma unroll
        for (int i = 0; i < 4; i++)
#pragma unroll
            for (int j = 0; j < 4; j++)
                acc[i][j] = __builtin_amdgcn_mfma_f32_16x16x32_bf16(af[i], bfr[j], acc[i][j], 0, 0, 0);
    }

    float bj[4];
#pragma unroll
    for (int j = 0; j < 4; j++) bj[j] = bias[col0 + wn * 64 + j * 16 + lm];
#pragma unroll
    for (int i = 0; i < 4; i++) {
        int rbase = row0 + wm * 64 + i * 16 + quad * 4;
#pragma unroll
        for (int j = 0; j < 4; j++) {
            int c = col0 + wn * 64 + j * 16 + lm;
#pragma unroll
            for (int r = 0; r < 4; r++) {
                float v = acc[i][j][r] + bj[j];
                if (gelu) v = 0.5f * v * (1.0f + erff(v * 0.70710678118f));
                size_t idx = (size_t)(rbase + r) * N + c;
                if (res) {
                    ((float*)C)[idx] = v + res[idx];
                } else {
                    ((u16*)C)[idx] = f2bf(v);
                }
            }
        }
    }
}

// ---------------------------------------------------------------------------
// GEMM 128x64 (BM=128, BN=64): for N=1024 outputs (proj, FC2) -> 512 blocks
// = 2 blocks/CU so cross-block wave overlap hides staging latency.
// 4 waves (2x2): wave tile 64x32, acc 4x2.
// ---------------------------------------------------------------------------
__global__ __launch_bounds__(256, 2) void gemm_bt64(
    const u16* __restrict__ A, const u16* __restrict__ Bt,
    const float* __restrict__ bias, const float* res,
    void* C, int N, int K, int lda, int gelu)
{
    __shared__ __align__(16) u16 sA[128 * 32];
    __shared__ __align__(16) u16 sB[64 * 32];
    const int tid  = threadIdx.x;
    const int wave = tid >> 6, lane = tid & 63;
    const int lm = lane & 15, quad = lane >> 4;
    const int wm = wave >> 1, wn = wave & 1;
    const int row0 = blockIdx.y * 128, col0 = blockIdx.x * 64;
    const int r16 = lane >> 2;
    const int c8  = (lane & 3) * 8;

    f32x4 acc[4][2];
#pragma unroll
    for (int i = 0; i < 4; i++)
#pragma unroll
        for (int j = 0; j < 2; j++) acc[i][j] = f32x4{0.f, 0.f, 0.f, 0.f};

    for (int k0 = 0; k0 < K; k0 += 32) {
        __syncthreads();
        // 12 chunks (8 A + 4 B), 3 per wave
#pragma unroll
        for (int j = 0; j < 3; j++) {
            int cid = wave * 3 + j;
            if (cid < 8) {
                int r = cid * 16 + r16;
                gload_lds16(A + (size_t)(row0 + r) * lda + k0 + c8, &sA[cid * 512]);
            } else {
                int bc = cid - 8;
                int r = bc * 16 + r16;
                gload_lds16(Bt + (size_t)(col0 + r) * K + k0 + c8, &sB[bc * 512]);
            }
        }
        WAIT_ALL();
        __syncthreads();

        bf16x8 af[4], bfr[2];
#pragma unroll
        for (int t = 0; t < 4; t++)
            af[t] = *(const bf16x8*)&sA[(wm * 64 + t * 16 + lm) * 32 + quad * 8];
#pragma unroll
        for (int t = 0; t < 2; t++)
            bfr[t] = *(const bf16x8*)&sB[(wn * 32 + t * 16 + lm) * 32 + quad * 8];
#pragma unroll
        for (int i = 0; i < 4; i++)
#pragma unroll
            for (int j = 0; j < 2; j++)
                acc[i][j] = __builtin_amdgcn_mfma_f32_16x16x32_bf16(af[i], bfr[j], acc[i][j], 0, 0, 0);
    }

    float bj[2];
#pragma unroll
    for (int j = 0; j < 2; j++) bj[j] = bias[col0 + wn * 32 + j * 16 + lm];
#pragma unroll
    for (int i = 0; i < 4; i++) {
        int rbase = row0 + wm * 64 + i * 16 + quad * 4;
#pragma unroll
        for (int j = 0; j < 2; j++) {
            int c = col0 + wn * 32 + j * 16 + lm;
#pragma unroll
            for (int r = 0; r < 4; r++) {
                float v = acc[i][j][r] + bj[j];
                if (gelu) v = 0.5f * v * (1.0f + erff(v * 0.70710678118f));
                size_t idx = (size_t)(rbase + r) * N + c;
                if (res) {
                    ((float*)C)[idx] = v + res[idx];
                } else {
                    ((u16*)C)[idx] = f2bf(v);
                }
            }
        }
    }
}

// ---------------------------------------------------------------------------
// Causal flash attention, IN-PLACE on qkv [4096][3072] bf16 (q|k|v, head h at
// col h*64). Output overwrites Q columns (own rows x own head's cols only).
// Block = 4 waves = 64 q rows of one (b,h); wave = 16 q rows.
// Grid 32x32 = 1024 blocks (~4/CU). Balance swizzle: pair-fold in x + y-flip
// so each CU's block set sums to ~constant K-tile work.
// sVT: chunk-XOR swizzle (stride 64, conflict-free, 16B-aligned b128 reads).
// sP: stride 72 elems = 144 B (16B-aligned, 2-way max on writes).
// ---------------------------------------------------------------------------
__global__ __launch_bounds__(256, 4) void attn_kernel(u16* qkv)
{
    __shared__ __align__(16) u16 sQ[64 * 64];      // 8 KB
    __shared__ __align__(16) u16 sK[64 * 64];      // 8 KB
    __shared__ __align__(16) u16 sVT[64 * 64];     // 8 KB (swizzled)
    __shared__ __align__(16) u16 sP[4 * 16 * 72];  // 9 KB (per-wave, pad 72)

    const int tid  = threadIdx.x;
    const int wave = tid >> 6, lane = tid & 63;
    const int lm = lane & 15, quad = lane >> 4;
    // balance swizzle
    int xi = blockIdx.x;
    int qz = (xi & 1) ? (31 - (xi >> 1)) : (xi >> 1);
    int qi = ((blockIdx.y >> 3) & 1) ? (31 - qz) : qz;
    const int q0 = qi * 64;
    const int b = blockIdx.y >> 4, h = blockIdx.y & 15;
    const size_t tok0 = (size_t)b * 2048;
    const int qcol = h * 64, kcol = 1024 + h * 64, vcol = 2048 + h * 64;
    const int r8 = lane >> 3;        // row within an 8-row staging chunk
    const int c8 = (lane & 7) * 8;   // element offset of this lane's 16B

    // stage Q (64x64): 8 chunks, 2 per wave
#pragma unroll
    for (int j = 0; j < 2; j++) {
        int chunk = wave * 2 + j;
        int r = chunk * 8 + r8;
        gload_lds16(qkv + (tok0 + q0 + r) * 3072 + qcol + c8, &sQ[chunk * 512]);
    }
    WAIT_ALL();
    __syncthreads();

    bf16x8 aq[2];
#pragma unroll
    for (int kk = 0; kk < 2; kk++)
        aq[kk] = *(const bf16x8*)&sQ[(wave * 16 + lm) * 64 + kk * 32 + quad * 8];

    f32x4 oacc[4];
    float mrun[4], lrun[4];
#pragma unroll
    for (int n = 0; n < 4; n++) oacc[n] = f32x4{0.f, 0.f, 0.f, 0.f};
#pragma unroll
    for (int r = 0; r < 4; r++) { mrun[r] = -1e30f; lrun[r] = 0.f; }

    // V-transpose constants: thread handles key=tid>>2, d in [dq, dq+16)
    const int vkey = tid >> 2;
    const int vdq  = (tid & 3) * 16;
    const int vpos = (((vkey >> 3) ^ (tid & 3)) << 3) | (vkey & 7); // swizzled col

    u16* sPw = &sP[wave * 16 * 72];
    const int ntiles = qi + 1;   // causal: K-tiles 0..qi

    for (int tk = 0; tk < ntiles; tk++) {
        const int kb = tk * 64;
        __syncthreads();   // prior iter's reads of sK/sVT complete
        // stage K (64x64): 8 chunks, 2 per wave
#pragma unroll
        for (int j = 0; j < 2; j++) {
            int chunk = wave * 2 + j;
            int r = chunk * 8 + r8;
            gload_lds16(qkv + (tok0 + kb + r) * 3072 + kcol + c8, &sK[chunk * 512]);
        }
        // stage V^T swizzled: V[k][d] -> sVT[d*64 + swz(k)]
        {
            const u16* vr = qkv + (tok0 + kb + vkey) * 3072 + vcol + vdq;
            u16x8 v0 = *(const u16x8*)vr;
            u16x8 v1 = *(const u16x8*)(vr + 8);
#pragma unroll
            for (int i = 0; i < 8; i++) sVT[(vdq + i) * 64 + vpos] = v0[i];
#pragma unroll
            for (int i = 0; i < 8; i++) sVT[(vdq + 8 + i) * 64 + vpos] = v1[i];
        }
        WAIT_ALL();
        __syncthreads();

        // S = (Q K^T) * scale, causal mask
        float sc[4][4];
#pragma unroll
        for (int n = 0; n < 4; n++) {
            f32x4 s = f32x4{0.f, 0.f, 0.f, 0.f};
#pragma unroll
            for (int kk = 0; kk < 2; kk++) {
                bf16x8 bk = *(const bf16x8*)&sK[(n * 16 + lm) * 64 + kk * 32 + quad * 8];
                s = __builtin_amdgcn_mfma_f32_16x16x32_bf16(aq[kk], bk, s, 0, 0, 0);
            }
            int col  = kb + n * 16 + lm;
            int rowb = q0 + wave * 16 + quad * 4;
#pragma unroll
            for (int r = 0; r < 4; r++)
                sc[n][r] = (col <= rowb + r) ? s[r] * 0.125f : -1e30f;
        }
        // online softmax (row stats replicated across the 16 lm-lanes)
#pragma unroll
        for (int r = 0; r < 4; r++) {
            float mx = fmaxf(fmaxf(sc[0][r], sc[1][r]), fmaxf(sc[2][r], sc[3][r]));
#pragma unroll
            for (int off = 1; off < 16; off <<= 1) mx = fmaxf(mx, __shfl_xor(mx, off));
            float mnew  = fmaxf(mrun[r], mx);
            float alpha = __expf(mrun[r] - mnew);
            float sum = 0.f;
#pragma unroll
            for (int n = 0; n < 4; n++) {
                float p = __expf(sc[n][r] - mnew);
                sc[n][r] = p;
                sum += p;
            }
#pragma unroll
            for (int off = 1; off < 16; off <<= 1) sum += __shfl_xor(sum, off);
            lrun[r] = lrun[r] * alpha + sum;
            mrun[r] = mnew;
#pragma unroll
            for (int n = 0; n < 4; n++) oacc[n][r] *= alpha;
        }
        // P: C-layout regs -> per-wave LDS (stride 72) -> A-layout frags
#pragma unroll
        for (int n = 0; n < 4; n++)
#pragma unroll
            for (int r = 0; r < 4; r++)
                sPw[(quad * 4 + r) * 72 + n * 16 + lm] = f2bf(sc[n][r]);
        bf16x8 ap[2];
#pragma unroll
        for (int kk = 0; kk < 2; kk++)
            ap[kk] = *(const bf16x8*)&sPw[lm * 72 + kk * 32 + quad * 8];
        // O += P V  (sVT read with chunk-XOR: chunk' = (kk*4+quad) ^ n)
#pragma unroll
        for (int n = 0; n < 4; n++)
#pragma unroll
            for (int kk = 0; kk < 2; kk++) {
                bf16x8 bv = *(const bf16x8*)
                    &sVT[(n * 16 + lm) * 64 + (((kk * 4 + quad) ^ n) << 3)];
                oacc[n] = __builtin_amdgcn_mfma_f32_16x16x32_bf16(ap[kk], bv, oacc[n], 0, 0, 0);
            }
    }

    // write O into the Q columns of qkv (in-place)
    {
        int rowb = q0 + wave * 16 + quad * 4;
#pragma unroll
        for (int r = 0; r < 4; r++) {
            float inv = 1.0f / lrun[r];
#pragma unroll
            for (int n = 0; n < 4; n++) {
                int d = n * 16 + lm;
                qkv[(tok0 + rowb + r) * 3072 + qcol + d] = f2bf(oacc[n][r] * inv);
            }
        }
    }
}

// ---------------------------------------------------------------------------
extern "C" void kernel_launch(void* const* d_in, const int* in_sizes, int n_in,
                              void* d_out, int out_size, void* d_ws, size_t ws_size,
                              hipStream_t stream)
{
    (void)in_sizes; (void)n_in; (void)out_size; (void)ws_size;
    const float* x    = (const float*)d_in[0];
    const float* ln1g = (const float*)d_in[1];
    const float* ln1b = (const float*)d_in[2];
    const float* qkvwF= (const float*)d_in[3];
    const float* qkvb = (const float*)d_in[4];
    const float* outwF= (const float*)d_in[5];
    const float* outb = (const float*)d_in[6];
    const float* ln2g = (const float*)d_in[7];
    const float* ln2b = (const float*)d_in[8];
    const float* fc1wF= (const float*)d_in[9];
    const float* fc1b = (const float*)d_in[10];
    const float* fc2wF= (const float*)d_in[11];
    const float* fc2b = (const float*)d_in[12];
    float* out = (float*)d_out;          // fp32 output / residual stream x1
    u16*   ws  = (u16*)d_ws;
    const int M1 = 1 << 20;

    // ws layout (u16 elems), total 28M = 56 MB:
    //   qkvw' [0,3M)  outw' [3M,4M)  qkvB [4M,16M)  fc1w' [16M,20M)
    //   fc2w' [20M,24M)  h [24M,28M)
    //   ff1 overlays [0,16M)  (qkvw'/outw'/qkvB all dead after step 4)
    u16* qkvw = ws;
    u16* outw = ws + 3 * M1;
    u16* qkvB = ws + 4 * M1;
    u16* ff1  = ws;
    u16* fc1w = ws + 16 * M1;
    u16* fc2w = ws + 20 * M1;
    u16* h    = ws + 24 * M1;

    // 0. convert the 4 big weights fp32 -> bf16
    cvt_kernel<<<3072, 256, 0, stream>>>(qkvwF, qkvw, 3 * M1 / 4);
    cvt_kernel<<<1024, 256, 0, stream>>>(outwF, outw, 1 * M1 / 4);
    cvt_kernel<<<4096, 256, 0, stream>>>(fc1wF, fc1w, 4 * M1 / 4);
    cvt_kernel<<<4096, 256, 0, stream>>>(fc2wF, fc2w, 4 * M1 / 4);

    // 1. h = LN1(x)
    ln_kernel<<<4096, 256, 0, stream>>>(x, ln1g, ln1b, h);
    // 2. qkvB = h @ qkv_w^T + qkv_b   (bf16 out; 768 blocks = 3/CU)
    gemm_bt<<<dim3(24, 32), 256, 0, stream>>>(h, qkvw, qkvb, nullptr, qkvB,
                                              3072, 1024, 1024, 0);
    // 3. causal flash attention (1024 blocks ~ 4/CU), O -> Q cols of qkvB
    attn_kernel<<<dim3(32, 32), 256, 0, stream>>>(qkvB);
    // 4. x1(=d_out, fp32) = x + O @ out_w^T + out_b   (512 blocks = 2/CU)
    gemm_bt64<<<dim3(16, 32), 256, 0, stream>>>(qkvB, outw, outb, x, out,
                                                1024, 1024, 3072, 0);
    // 5. h = LN2(x1)
    ln_kernel<<<4096, 256, 0, stream>>>(out, ln2g, ln2b, h);
    // 6. ff1 = gelu(h @ fc1_w^T + fc1_b)   (bf16; 1024 blocks = 4/CU)
    gemm_bt<<<dim3(32, 32), 256, 0, stream>>>(h, fc1w, fc1b, nullptr, ff1,
                                              4096, 1024, 1024, 1);
    // 7. out = x1 + ff1 @ fc2_w^T + fc2_b   (fp32 in-place; 512 blocks = 2/CU)
    gemm_bt64<<<dim3(16, 32), 256, 0, stream>>>(ff1, fc2w, fc2b, out, out,
                                                1024, 4096, 4096, 0);
}

// Round 6
// 401.760 us; speedup vs baseline: 1.2121x; 1.0935x over previous
//
#include <hip/hip_runtime.h>
#include <stdint.h>

typedef uint16_t u16;
typedef uint32_t u32;
typedef __bf16 bf16_t;
typedef bf16_t bf16x8 __attribute__((ext_vector_type(8)));
typedef float f32x4 __attribute__((ext_vector_type(4)));
typedef u16 u16x4 __attribute__((ext_vector_type(4)));
typedef u16 u16x8 __attribute__((ext_vector_type(8)));

__device__ __forceinline__ float bf2f(u16 v) {
    union { u32 u; float f; } x; x.u = ((u32)v) << 16; return x.f;
}
__device__ __forceinline__ u16 f2bf(float f) {
    union { float f; u32 u; } x; x.f = f;
    u32 r = (x.u + 0x7fffu + ((x.u >> 16) & 1u)) >> 16;
    return (u16)r;
}

// async 16B/lane global->LDS. HW writes lane i at (wave-uniform lds base)+i*16.
__device__ __forceinline__ void gload_lds16(const u16* g, u16* l) {
    __builtin_amdgcn_global_load_lds(
        (const __attribute__((address_space(1))) void*)g,
        (__attribute__((address_space(3))) void*)l,
        16, 0, 0);
}
#define WAIT_ALL() __builtin_amdgcn_s_waitcnt(0)
// wait until <= n vector-memory ops outstanding; expcnt/lgkmcnt unconstrained
// gfx9 encoding: vmcnt[3:0] | expcnt[6:4]=7 | lgkmcnt[11:8]=15
#define WAITVM(n) __builtin_amdgcn_s_waitcnt(0x0F70 | (n))
#define BARRIER() __builtin_amdgcn_s_barrier()

// ---------------------------------------------------------------------------
// Convert fp32 -> bf16, vectorized x4.
// ---------------------------------------------------------------------------
__global__ __launch_bounds__(256) void cvt_kernel(
    const float* __restrict__ src, u16* __restrict__ dst, int n4)
{
    int i = blockIdx.x * 256 + threadIdx.x;
    if (i >= n4) return;
    f32x4 v = ((const f32x4*)src)[i];
    u16x4 o;
#pragma unroll
    for (int j = 0; j < 4; j++) o[j] = f2bf(v[j]);
    ((u16x4*)dst)[i] = o;
}

// ---------------------------------------------------------------------------
// LayerNorm over D=1024, one block (256 thr) per token row. fp32 in, bf16 out.
// ---------------------------------------------------------------------------
__global__ __launch_bounds__(256) void ln_kernel(
    const float* __restrict__ x, const float* __restrict__ g,
    const float* __restrict__ b, u16* __restrict__ out)
{
    const int row = blockIdx.x;
    const int tid = threadIdx.x;
    f32x4 xv = *(const f32x4*)(x + (size_t)row * 1024 + tid * 4);
    float v[4];
    float s = 0.f, s2 = 0.f;
#pragma unroll
    for (int i = 0; i < 4; i++) { v[i] = xv[i]; s += v[i]; s2 += v[i] * v[i]; }
#pragma unroll
    for (int off = 1; off < 64; off <<= 1) {
        s  += __shfl_xor(s, off);
        s2 += __shfl_xor(s2, off);
    }
    __shared__ float ws1[4], ws2[4];
    if ((tid & 63) == 0) { ws1[tid >> 6] = s; ws2[tid >> 6] = s2; }
    __syncthreads();
    s  = ws1[0] + ws1[1] + ws1[2] + ws1[3];
    s2 = ws2[0] + ws2[1] + ws2[2] + ws2[3];
    float mu  = s * (1.0f / 1024.0f);
    float var = s2 * (1.0f / 1024.0f) - mu * mu;
    float rstd = rsqrtf(var + 1e-5f);
    f32x4 gv = *(const f32x4*)(g + tid * 4);
    f32x4 bv = *(const f32x4*)(b + tid * 4);
    u16x4 ov;
#pragma unroll
    for (int i = 0; i < 4; i++)
        ov[i] = f2bf((v[i] - mu) * rstd * gv[i] + bv[i]);
    *(u16x4*)(out + (size_t)row * 1024 + tid * 4) = ov;
}

// ---------------------------------------------------------------------------
// Pipelined GEMM 128x128: C = A @ Bt^T + bias (+gelu) (+fp32 residual).
// Double-buffered LDS; raw s_barrier + per-wave partial vmcnt so next tile's
// global_load_lds stays in flight across the compute phase (no full drain).
// ---------------------------------------------------------------------------
__global__ __launch_bounds__(256, 2) void gemm_bt(
    const u16* __restrict__ A, const u16* __restrict__ Bt,
    const float* __restrict__ bias, const float* res,
    void* C, int N, int K, int lda, int gelu)
{
    __shared__ __align__(16) u16 sA[2][128 * 32];
    __shared__ __align__(16) u16 sB[2][128 * 32];
    const int tid  = threadIdx.x;
    const int wave = tid >> 6, lane = tid & 63;
    const int lm = lane & 15, quad = lane >> 4;
    const int wm = wave >> 1, wn = wave & 1;
    const int row0 = blockIdx.y * 128, col0 = blockIdx.x * 128;
    const int r16 = lane >> 2;
    const int c8  = (lane & 3) * 8;
    const int niter = K >> 5;

    // per-wave staging pointers (wave 0/1: A chunks, wave 2/3: B chunks)
    const u16* gsrc;
    size_t gstride;
    int chunk0;
    if (wave < 2) {
        chunk0 = wave * 4;
        gsrc = A + (size_t)(row0 + chunk0 * 16 + r16) * lda + c8;
        gstride = lda;
    } else {
        chunk0 = (wave - 2) * 4;
        gsrc = Bt + (size_t)(col0 + chunk0 * 16 + r16) * K + c8;
        gstride = K;
    }
    u16* lbase0 = (wave < 2) ? &sA[0][chunk0 * 512] : &sB[0][chunk0 * 512];
    u16* lbase1 = (wave < 2) ? &sA[1][chunk0 * 512] : &sB[1][chunk0 * 512];

    f32x4 acc[4][4];
#pragma unroll
    for (int i = 0; i < 4; i++)
#pragma unroll
        for (int j = 0; j < 4; j++) acc[i][j] = f32x4{0.f, 0.f, 0.f, 0.f};

    // prologue: tile 0 -> buf 0
#pragma unroll
    for (int j = 0; j < 4; j++)
        gload_lds16(gsrc + (size_t)(j * 16) * gstride, lbase0 + j * 512);

    for (int k = 0; k < niter; k++) {
        const int cur = k & 1;
        if (k + 1 < niter) {
            const u16* gs = gsrc + (size_t)(k + 1) * 32;
            u16* lb = cur ? lbase0 : lbase1;
#pragma unroll
            for (int j = 0; j < 4; j++)
                gload_lds16(gs + (size_t)(j * 16) * gstride, lb + j * 512);
            WAITVM(4);   // own tile-k loads done; tile-k+1's 4 stay in flight
        } else {
            WAITVM(0);
        }
        BARRIER();       // all waves' tile-k loads complete

        bf16x8 af[4], bfr[4];
#pragma unroll
        for (int t = 0; t < 4; t++)
            af[t] = *(const bf16x8*)&sA[cur][(wm * 64 + t * 16 + lm) * 32 + quad * 8];
#pragma unroll
        for (int t = 0; t < 4; t++)
            bfr[t] = *(const bf16x8*)&sB[cur][(wn * 64 + t * 16 + lm) * 32 + quad * 8];
#pragma unroll
        for (int i = 0; i < 4; i++)
#pragma unroll
            for (int j = 0; j < 4; j++)
                acc[i][j] = __builtin_amdgcn_mfma_f32_16x16x32_bf16(af[i], bfr[j], acc[i][j], 0, 0, 0);

        BARRIER();       // all waves done reading buf[cur] before it's reused
    }

    float bj[4];
#pragma unroll
    for (int j = 0; j < 4; j++) bj[j] = bias[col0 + wn * 64 + j * 16 + lm];
#pragma unroll
    for (int i = 0; i < 4; i++) {
        int rbase = row0 + wm * 64 + i * 16 + quad * 4;
#pragma unroll
        for (int j = 0; j < 4; j++) {
            int c = col0 + wn * 64 + j * 16 + lm;
#pragma unroll
            for (int r = 0; r < 4; r++) {
                float v = acc[i][j][r] + bj[j];
                if (gelu) v = 0.5f * v * (1.0f + erff(v * 0.70710678118f));
                size_t idx = (size_t)(rbase + r) * N + c;
                if (res) {
                    ((float*)C)[idx] = v + res[idx];
                } else {
                    ((u16*)C)[idx] = f2bf(v);
                }
            }
        }
    }
}

// ---------------------------------------------------------------------------
// Pipelined GEMM 128x64 (BM=128, BN=64) for N=1024 outputs (proj, FC2):
// 512 blocks = 2 blocks/CU. Same double-buffer + raw-barrier pipeline;
// 12 chunks/tile, 3 per wave -> WAITVM(3).
// ---------------------------------------------------------------------------
__global__ __launch_bounds__(256, 2) void gemm_bt64(
    const u16* __restrict__ A, const u16* __restrict__ Bt,
    const float* __restrict__ bias, const float* res,
    void* C, int N, int K, int lda, int gelu)
{
    __shared__ __align__(16) u16 sA[2][128 * 32];
    __shared__ __align__(16) u16 sB[2][64 * 32];
    const int tid  = threadIdx.x;
    const int wave = tid >> 6, lane = tid & 63;
    const int lm = lane & 15, quad = lane >> 4;
    const int wm = wave >> 1, wn = wave & 1;
    const int row0 = blockIdx.y * 128, col0 = blockIdx.x * 64;
    const int r16 = lane >> 2;
    const int c8  = (lane & 3) * 8;
    const int niter = K >> 5;

    // per-wave staging: 3 chunks each; chunks 0..7 = A, 8..11 = B
    const u16* gs_[3];
    u16* lb0_[3];
    u16* lb1_[3];
    size_t gstride_[3];
#pragma unroll
    for (int j = 0; j < 3; j++) {
        int cid = wave * 3 + j;
        if (cid < 8) {
            gs_[j] = A + (size_t)(row0 + cid * 16 + r16) * lda + c8;
            gstride_[j] = lda;
            lb0_[j] = &sA[0][cid * 512];
            lb1_[j] = &sA[1][cid * 512];
        } else {
            int bc = cid - 8;
            gs_[j] = Bt + (size_t)(col0 + bc * 16 + r16) * K + c8;
            gstride_[j] = K;
            lb0_[j] = &sB[0][bc * 512];
            lb1_[j] = &sB[1][bc * 512];
        }
    }

    f32x4 acc[4][2];
#pragma unroll
    for (int i = 0; i < 4; i++)
#pragma unroll
        for (int j = 0; j < 2; j++) acc[i][j] = f32x4{0.f, 0.f, 0.f, 0.f};

    // prologue: tile 0 -> buf 0
#pragma unroll
    for (int j = 0; j < 3; j++) gload_lds16(gs_[j], lb0_[j]);

    for (int k = 0; k < niter; k++) {
        const int cur = k & 1;
        if (k + 1 < niter) {
#pragma unroll
            for (int j = 0; j < 3; j++)
                gload_lds16(gs_[j] + (size_t)(k + 1) * 32, cur ? lb0_[j] : lb1_[j]);
            WAITVM(3);
        } else {
            WAITVM(0);
        }
        BARRIER();

        bf16x8 af[4], bfr[2];
#pragma unroll
        for (int t = 0; t < 4; t++)
            af[t] = *(const bf16x8*)&sA[cur][(wm * 64 + t * 16 + lm) * 32 + quad * 8];
#pragma unroll
        for (int t = 0; t < 2; t++)
            bfr[t] = *(const bf16x8*)&sB[cur][(wn * 32 + t * 16 + lm) * 32 + quad * 8];
#pragma unroll
        for (int i = 0; i < 4; i++)
#pragma unroll
            for (int j = 0; j < 2; j++)
                acc[i][j] = __builtin_amdgcn_mfma_f32_16x16x32_bf16(af[i], bfr[j], acc[i][j], 0, 0, 0);

        BARRIER();
    }

    float bj[2];
#pragma unroll
    for (int j = 0; j < 2; j++) bj[j] = bias[col0 + wn * 32 + j * 16 + lm];
#pragma unroll
    for (int i = 0; i < 4; i++) {
        int rbase = row0 + wm * 64 + i * 16 + quad * 4;
#pragma unroll
        for (int j = 0; j < 2; j++) {
            int c = col0 + wn * 32 + j * 16 + lm;
#pragma unroll
            for (int r = 0; r < 4; r++) {
                float v = acc[i][j][r] + bj[j];
                if (gelu) v = 0.5f * v * (1.0f + erff(v * 0.70710678118f));
                size_t idx = (size_t)(rbase + r) * N + c;
                if (res) {
                    ((float*)C)[idx] = v + res[idx];
                } else {
                    ((u16*)C)[idx] = f2bf(v);
                }
            }
        }
    }
}

// ---------------------------------------------------------------------------
// Causal flash attention, IN-PLACE on qkv [4096][3072] bf16 (q|k|v, head h at
// col h*64). Output overwrites Q columns (own rows x own head's cols only).
// Block = 4 waves = 64 q rows of one (b,h); wave = 16 q rows.
// Grid 32x32 = 1024 blocks (~4/CU). Balance swizzle: pair-fold in x + y-flip.
// sVT: chunk-XOR swizzle; sP: stride 72 (144 B, 16B-aligned).
// ---------------------------------------------------------------------------
__global__ __launch_bounds__(256, 4) void attn_kernel(u16* qkv)
{
    __shared__ __align__(16) u16 sQ[64 * 64];
    __shared__ __align__(16) u16 sK[64 * 64];
    __shared__ __align__(16) u16 sVT[64 * 64];
    __shared__ __align__(16) u16 sP[4 * 16 * 72];

    const int tid  = threadIdx.x;
    const int wave = tid >> 6, lane = tid & 63;
    const int lm = lane & 15, quad = lane >> 4;
    int xi = blockIdx.x;
    int qz = (xi & 1) ? (31 - (xi >> 1)) : (xi >> 1);
    int qi = ((blockIdx.y >> 3) & 1) ? (31 - qz) : qz;
    const int q0 = qi * 64;
    const int b = blockIdx.y >> 4, h = blockIdx.y & 15;
    const size_t tok0 = (size_t)b * 2048;
    const int qcol = h * 64, kcol = 1024 + h * 64, vcol = 2048 + h * 64;
    const int r8 = lane >> 3;
    const int c8 = (lane & 7) * 8;

#pragma unroll
    for (int j = 0; j < 2; j++) {
        int chunk = wave * 2 + j;
        int r = chunk * 8 + r8;
        gload_lds16(qkv + (tok0 + q0 + r) * 3072 + qcol + c8, &sQ[chunk * 512]);
    }
    WAIT_ALL();
    __syncthreads();

    bf16x8 aq[2];
#pragma unroll
    for (int kk = 0; kk < 2; kk++)
        aq[kk] = *(const bf16x8*)&sQ[(wave * 16 + lm) * 64 + kk * 32 + quad * 8];

    f32x4 oacc[4];
    float mrun[4], lrun[4];
#pragma unroll
    for (int n = 0; n < 4; n++) oacc[n] = f32x4{0.f, 0.f, 0.f, 0.f};
#pragma unroll
    for (int r = 0; r < 4; r++) { mrun[r] = -1e30f; lrun[r] = 0.f; }

    const int vkey = tid >> 2;
    const int vdq  = (tid & 3) * 16;
    const int vpos = (((vkey >> 3) ^ (tid & 3)) << 3) | (vkey & 7);

    u16* sPw = &sP[wave * 16 * 72];
    const int ntiles = qi + 1;

    for (int tk = 0; tk < ntiles; tk++) {
        const int kb = tk * 64;
        __syncthreads();
#pragma unroll
        for (int j = 0; j < 2; j++) {
            int chunk = wave * 2 + j;
            int r = chunk * 8 + r8;
            gload_lds16(qkv + (tok0 + kb + r) * 3072 + kcol + c8, &sK[chunk * 512]);
        }
        {
            const u16* vr = qkv + (tok0 + kb + vkey) * 3072 + vcol + vdq;
            u16x8 v0 = *(const u16x8*)vr;
            u16x8 v1 = *(const u16x8*)(vr + 8);
#pragma unroll
            for (int i = 0; i < 8; i++) sVT[(vdq + i) * 64 + vpos] = v0[i];
#pragma unroll
            for (int i = 0; i < 8; i++) sVT[(vdq + 8 + i) * 64 + vpos] = v1[i];
        }
        WAIT_ALL();
        __syncthreads();

        float sc[4][4];
#pragma unroll
        for (int n = 0; n < 4; n++) {
            f32x4 s = f32x4{0.f, 0.f, 0.f, 0.f};
#pragma unroll
            for (int kk = 0; kk < 2; kk++) {
                bf16x8 bk = *(const bf16x8*)&sK[(n * 16 + lm) * 64 + kk * 32 + quad * 8];
                s = __builtin_amdgcn_mfma_f32_16x16x32_bf16(aq[kk], bk, s, 0, 0, 0);
            }
            int col  = kb + n * 16 + lm;
            int rowb = q0 + wave * 16 + quad * 4;
#pragma unroll
            for (int r = 0; r < 4; r++)
                sc[n][r] = (col <= rowb + r) ? s[r] * 0.125f : -1e30f;
        }
#pragma unroll
        for (int r = 0; r < 4; r++) {
            float mx = fmaxf(fmaxf(sc[0][r], sc[1][r]), fmaxf(sc[2][r], sc[3][r]));
#pragma unroll
            for (int off = 1; off < 16; off <<= 1) mx = fmaxf(mx, __shfl_xor(mx, off));
            float mnew  = fmaxf(mrun[r], mx);
            float alpha = __expf(mrun[r] - mnew);
            float sum = 0.f;
#pragma unroll
            for (int n = 0; n < 4; n++) {
                float p = __expf(sc[n][r] - mnew);
                sc[n][r] = p;
                sum += p;
            }
#pragma unroll
            for (int off = 1; off < 16; off <<= 1) sum += __shfl_xor(sum, off);
            lrun[r] = lrun[r] * alpha + sum;
            mrun[r] = mnew;
#pragma unroll
            for (int n = 0; n < 4; n++) oacc[n][r] *= alpha;
        }
#pragma unroll
        for (int n = 0; n < 4; n++)
#pragma unroll
            for (int r = 0; r < 4; r++)
                sPw[(quad * 4 + r) * 72 + n * 16 + lm] = f2bf(sc[n][r]);
        bf16x8 ap[2];
#pragma unroll
        for (int kk = 0; kk < 2; kk++)
            ap[kk] = *(const bf16x8*)&sPw[lm * 72 + kk * 32 + quad * 8];
#pragma unroll
        for (int n = 0; n < 4; n++)
#pragma unroll
            for (int kk = 0; kk < 2; kk++) {
                bf16x8 bv = *(const bf16x8*)
                    &sVT[(n * 16 + lm) * 64 + (((kk * 4 + quad) ^ n) << 3)];
                oacc[n] = __builtin_amdgcn_mfma_f32_16x16x32_bf16(ap[kk], bv, oacc[n], 0, 0, 0);
            }
    }

    {
        int rowb = q0 + wave * 16 + quad * 4;
#pragma unroll
        for (int r = 0; r < 4; r++) {
            float inv = 1.0f / lrun[r];
#pragma unroll
            for (int n = 0; n < 4; n++) {
                int d = n * 16 + lm;
                qkv[(tok0 + rowb + r) * 3072 + qcol + d] = f2bf(oacc[n][r] * inv);
            }
        }
    }
}

// ---------------------------------------------------------------------------
extern "C" void kernel_launch(void* const* d_in, const int* in_sizes, int n_in,
                              void* d_out, int out_size, void* d_ws, size_t ws_size,
                              hipStream_t stream)
{
    (void)in_sizes; (void)n_in; (void)out_size; (void)ws_size;
    const float* x    = (const float*)d_in[0];
    const float* ln1g = (const float*)d_in[1];
    const float* ln1b = (const float*)d_in[2];
    const float* qkvwF= (const float*)d_in[3];
    const float* qkvb = (const float*)d_in[4];
    const float* outwF= (const float*)d_in[5];
    const float* outb = (const float*)d_in[6];
    const float* ln2g = (const float*)d_in[7];
    const float* ln2b = (const float*)d_in[8];
    const float* fc1wF= (const float*)d_in[9];
    const float* fc1b = (const float*)d_in[10];
    const float* fc2wF= (const float*)d_in[11];
    const float* fc2b = (const float*)d_in[12];
    float* out = (float*)d_out;
    u16*   ws  = (u16*)d_ws;
    const int M1 = 1 << 20;

    u16* qkvw = ws;
    u16* outw = ws + 3 * M1;
    u16* qkvB = ws + 4 * M1;
    u16* ff1  = ws;
    u16* fc1w = ws + 16 * M1;
    u16* fc2w = ws + 20 * M1;
    u16* h    = ws + 24 * M1;

    cvt_kernel<<<3072, 256, 0, stream>>>(qkvwF, qkvw, 3 * M1 / 4);
    cvt_kernel<<<1024, 256, 0, stream>>>(outwF, outw, 1 * M1 / 4);
    cvt_kernel<<<4096, 256, 0, stream>>>(fc1wF, fc1w, 4 * M1 / 4);
    cvt_kernel<<<4096, 256, 0, stream>>>(fc2wF, fc2w, 4 * M1 / 4);

    ln_kernel<<<4096, 256, 0, stream>>>(x, ln1g, ln1b, h);
    gemm_bt<<<dim3(24, 32), 256, 0, stream>>>(h, qkvw, qkvb, nullptr, qkvB,
                                              3072, 1024, 1024, 0);
    attn_kernel<<<dim3(32, 32), 256, 0, stream>>>(qkvB);
    gemm_bt64<<<dim3(16, 32), 256, 0, stream>>>(qkvB, outw, outb, x, out,
                                                1024, 1024, 3072, 0);
    ln_kernel<<<4096, 256, 0, stream>>>(out, ln2g, ln2b, h);
    gemm_bt<<<dim3(32, 32), 256, 0, stream>>>(h, fc1w, fc1b, nullptr, ff1,
                                              4096, 1024, 1024, 1);
    gemm_bt64<<<dim3(16, 32), 256, 0, stream>>>(ff1, fc2w, fc2b, out, out,
                                                1024, 4096, 4096, 0);
}